// Round 2
// baseline (242.738 us; speedup 1.0000x reference)
//
#include <hip/hip_runtime.h>
#include <hip/hip_bf16.h>

#define D_ 128
#define N_ 8192
#define K_ 256

typedef __attribute__((ext_vector_type(8))) short sh8;   // 8 bf16 = 4 VGPRs
typedef __attribute__((ext_vector_type(4))) float f4;    // 4 fp32

__device__ __forceinline__ unsigned short f2bf(float f) {
  union { float f; unsigned u; } x; x.f = f;
  unsigned r = x.u + 0x7fffu + ((x.u >> 16) & 1u);       // RNE
  return (unsigned short)(r >> 16);
}

// ---------------------------------------------------------------------------
// prep_x: X (fp32 [D][N]) -> Xbt (bf16 [N][D]) transpose, and copy X -> out rows 0..D-1
// grid (N/64, D/64), block 256
__global__ void prep_x_k(const float* __restrict__ X, float* __restrict__ out,
                         unsigned short* __restrict__ Xbt) {
  __shared__ float tile[64][65];
  const int n0 = blockIdx.x * 64;
  const int e0 = blockIdx.y * 64;
  const int t = threadIdx.x;
  const int col = t & 63;
  const int r4 = t >> 6;
  for (int rr = 0; rr < 64; rr += 4) {
    int e = rr + r4;
    float v = X[(size_t)(e0 + e) * N_ + n0 + col];
    tile[e][col] = v;
    out[(size_t)(e0 + e) * N_ + n0 + col] = v;   // exact fp32 copy of X
  }
  __syncthreads();
  const int chunk = t & 15;
  for (int iter = 0; iter < 4; ++iter) {
    int nl = iter * 16 + (t >> 4);
    ushort4 w;
    w.x = f2bf(tile[chunk * 4 + 0][nl]);
    w.y = f2bf(tile[chunk * 4 + 1][nl]);
    w.z = f2bf(tile[chunk * 4 + 2][nl]);
    w.w = f2bf(tile[chunk * 4 + 3][nl]);
    *(ushort4*)&Xbt[(size_t)(n0 + nl) * D_ + e0 + chunk * 4] = w;
  }
}

// ---------------------------------------------------------------------------
// prep_a: N_A (fp32 [D][D][K], layout d,e,c) -> Ab (bf16 [K][D][D], layout c,d,e)
// grid (K/64, D/64, D), block 256
__global__ void prep_a_k(const float* __restrict__ NA, unsigned short* __restrict__ Ab) {
  __shared__ float tile[64][65];   // [e][c]
  const int c0 = blockIdx.x * 64;
  const int e0 = blockIdx.y * 64;
  const int d  = blockIdx.z;
  const int t = threadIdx.x;
  const int cc = t & 63;
  const int r4 = t >> 6;
  const size_t dbase = (size_t)d * D_ * K_;
  for (int rr = 0; rr < 64; rr += 4) {
    int e = rr + r4;
    tile[e][cc] = NA[dbase + (size_t)(e0 + e) * K_ + c0 + cc];
  }
  __syncthreads();
  const int chunk = t & 15;
  for (int iter = 0; iter < 4; ++iter) {
    int cl = iter * 16 + (t >> 4);
    ushort4 w;
    w.x = f2bf(tile[chunk * 4 + 0][cl]);
    w.y = f2bf(tile[chunk * 4 + 1][cl]);
    w.z = f2bf(tile[chunk * 4 + 2][cl]);
    w.w = f2bf(tile[chunk * 4 + 3][cl]);
    *(ushort4*)&Ab[(size_t)(c0 + cl) * D_ * D_ + (size_t)d * D_ + e0 + chunk * 4] = w;
  }
}

// ---------------------------------------------------------------------------
// amu: Amut[c][d] = sum_e N_A[d][e][c] * N_mu[e][c]   (fp32, exact)
// grid (D), block (K). 4 accumulators to break the serial fma chain.
__global__ void amu_k(const float* __restrict__ NA, const float* __restrict__ Nmu,
                      float* __restrict__ Amut) {
  const int d = blockIdx.x;
  const int c = threadIdx.x;
  const size_t dbase = (size_t)d * D_ * K_;
  float s0 = 0.f, s1 = 0.f, s2 = 0.f, s3 = 0.f;
#pragma unroll 8
  for (int e = 0; e < 32; ++e) {
    s0 += NA[dbase + (size_t)(e +  0) * K_ + c] * Nmu[(size_t)(e +  0) * K_ + c];
    s1 += NA[dbase + (size_t)(e + 32) * K_ + c] * Nmu[(size_t)(e + 32) * K_ + c];
    s2 += NA[dbase + (size_t)(e + 64) * K_ + c] * Nmu[(size_t)(e + 64) * K_ + c];
    s3 += NA[dbase + (size_t)(e + 96) * K_ + c] * Nmu[(size_t)(e + 96) * K_ + c];
  }
  Amut[(size_t)c * D_ + d] = (s0 + s1) + (s2 + s3);
}

// ---------------------------------------------------------------------------
// main: for each (n-tile of 128, c-chunk of 32):
//   sq[c][n] = sum_d (sum_e A[d,e,c] X[e,n] - Amu[d,c])^2
// grid (N/128, K/32), block 512 (8 waves). Wave (wd, wj): d in [wd*32, wd*32+32),
// j in [wj*64, wj*64+64). Registers halved vs prior round -> 4 waves/SIMD.
__global__ __launch_bounds__(512, 4) void main_k(
    const unsigned short* __restrict__ Ab, const unsigned short* __restrict__ Xbt,
    const float* __restrict__ Amut, float* __restrict__ sqws) {
  __shared__ float sqred[2][4][128];
  const int t = threadIdx.x;
  const int w = t >> 6;
  const int L = t & 63;
  const int m = L & 15;        // MFMA row/col lane index
  const int q = L >> 4;        // quad
  const int wd = w & 3;        // d-split (4 x 32 rows)
  const int wj = w >> 2;       // j-split (2 x 64 cols)
  const int n0 = blockIdx.x * 128;
  const int c0 = blockIdx.y * 32;

  // X B-fragments in registers for entire c-loop: B[k=e][n=j]; lane holds
  // n = wj*64 + jt*16 + m, k = ks*32 + q*8 + i  -> contiguous 16B from Xbt[n][e]
  sh8 xf[4][4];
  {
    const unsigned short* xb = Xbt + (size_t)(n0 + wj * 64 + m) * D_ + q * 8;
#pragma unroll
    for (int jt = 0; jt < 4; ++jt)
#pragma unroll
      for (int ks = 0; ks < 4; ++ks)
        xf[jt][ks] = *(const sh8*)&xb[(size_t)jt * 16 * D_ + ks * 32];
  }

  const unsigned short* Ap = Ab + (size_t)c0 * D_ * D_ + (size_t)(wd * 32 + m) * D_ + q * 8;
  const float* amup = Amut + (size_t)c0 * D_ + wd * 32 + q * 4;

  const f4 zero = {0.f, 0.f, 0.f, 0.f};

  for (int ci = 0; ci < 32; ++ci) {
    f4 amu0 = *(const f4*)amup;
    f4 amu1 = *(const f4*)(amup + 16);

    f4 acc[2][4];
#pragma unroll
    for (int jt = 0; jt < 4; ++jt) { acc[0][jt] = zero; acc[1][jt] = zero; }

#pragma unroll
    for (int ks = 0; ks < 4; ++ks) {
      sh8 a0 = *(const sh8*)&Ap[ks * 32];
      sh8 a1 = *(const sh8*)&Ap[(size_t)16 * D_ + ks * 32];
#pragma unroll
      for (int jt = 0; jt < 4; ++jt) {
        acc[0][jt] = __builtin_amdgcn_mfma_f32_16x16x32_bf16(a0, xf[jt][ks], acc[0][jt], 0, 0, 0);
        acc[1][jt] = __builtin_amdgcn_mfma_f32_16x16x32_bf16(a1, xf[jt][ks], acc[1][jt], 0, 0, 0);
      }
    }

    // epilogue: subtract Amu, square, reduce over this wave's 32 d rows.
    // C/D layout: col j = wj*64 + jt*16 + m, row d = wd*32 + (tile16)*16 + q*4 + r
    float ps[4];
#pragma unroll
    for (int jt = 0; jt < 4; ++jt) {
      float s = 0.f;
#pragma unroll
      for (int r = 0; r < 4; ++r) {
        float v0 = acc[0][jt][r] - amu0[r];
        float v1 = acc[1][jt][r] - amu1[r];
        s += v0 * v0 + v1 * v1;
      }
      s += __shfl_xor(s, 16, 64);   // combine quad pairs
      s += __shfl_xor(s, 32, 64);   // full 32-d sum, replicated over q
      ps[jt] = s;
    }
    // lane (q,m) stores column j = wj*64 + q*16 + m  (value in ps[q])
    float sel = (q == 0) ? ps[0] : (q == 1) ? ps[1] : (q == 2) ? ps[2] : ps[3];
    const int buf = ci & 1;
    sqred[buf][wd][wj * 64 + q * 16 + m] = sel;
    __syncthreads();
    if (t < 128) {
      float s = sqred[buf][0][t] + sqred[buf][1][t] + sqred[buf][2][t] + sqred[buf][3][t];
      sqws[(size_t)(c0 + ci) * N_ + n0 + t] = s;
    }
    Ap += D_ * D_;
    amup += D_;
  }
}

// ---------------------------------------------------------------------------
// softmax over c per n; writes Pi to out rows D_..D_+K_-1
// grid (N/32), block 256. thread t: n_loc = t&31, c-group = t>>5 (32 c each)
__global__ __launch_bounds__(256) void softmax_k(const float* __restrict__ sqws,
                                                 const float* __restrict__ gptr,
                                                 float* __restrict__ out) {
  __shared__ float s_ld[K_][32];   // 32 KB
  __shared__ float red[8][32];
  __shared__ float red2[8][32];
  const int t = threadIdx.x;
  const int n0 = blockIdx.x * 32;
  const float gamma = *gptr;
  const int nl = t & 31;
  const int cg = t >> 5;           // 8 groups of 32 c
  // load all sq for 32 n
  for (int it = 0; it < 32; ++it) {
    int c = it * 8 + cg;
    s_ld[c][nl] = sqws[(size_t)c * N_ + n0 + nl];
  }
  __syncthreads();
  // pass 1: max of gamma*s over this thread's 32 c
  float mxp = -1e30f;
  for (int cc = 0; cc < 32; ++cc)
    mxp = fmaxf(mxp, gamma * s_ld[cg * 32 + cc][nl]);
  red[cg][nl] = mxp;
  __syncthreads();
  float mx = red[0][nl];
#pragma unroll
  for (int g2 = 1; g2 < 8; ++g2) mx = fmaxf(mx, red[g2][nl]);
  // pass 2: exp and partial sum
  float z = 0.f;
  for (int cc = 0; cc < 32; ++cc) {
    int c = cg * 32 + cc;
    float e = __expf(gamma * s_ld[c][nl] - mx);
    s_ld[c][nl] = e;
    z += e;
  }
  red2[cg][nl] = z;
  __syncthreads();
  float zz = red2[0][nl];
#pragma unroll
  for (int g2 = 1; g2 < 8; ++g2) zz += red2[g2][nl];
  float rz = 1.f / zz;
  // pass 3: write Pi
  for (int cc = 0; cc < 32; ++cc) {
    int c = cg * 32 + cc;
    out[(size_t)(D_ + c) * N_ + n0 + nl] = s_ld[c][nl] * rz;
  }
}

// ---------------------------------------------------------------------------
extern "C" void kernel_launch(void* const* d_in, const int* in_sizes, int n_in,
                              void* d_out, int out_size, void* d_ws, size_t ws_size,
                              hipStream_t stream) {
  const float* X   = (const float*)d_in[0];
  const float* NA  = (const float*)d_in[1];
  const float* Nmu = (const float*)d_in[2];
  const float* g   = (const float*)d_in[3];
  float* out = (float*)d_out;
  char* ws = (char*)d_ws;

  unsigned short* Xbt = (unsigned short*)(ws);                 // 2 MB
  unsigned short* Ab  = (unsigned short*)(ws + 2097152);       // 8.39 MB
  float* Amut         = (float*)(ws + 10485760);               // 128 KB
  float* sqws         = (float*)(ws + 10616832);               // 8.39 MB

  hipLaunchKernelGGL(prep_x_k, dim3(N_ / 64, D_ / 64), dim3(256), 0, stream, X, out, Xbt);
  hipLaunchKernelGGL(prep_a_k, dim3(K_ / 64, D_ / 64, D_), dim3(256), 0, stream, NA, Ab);
  hipLaunchKernelGGL(amu_k, dim3(D_), dim3(K_), 0, stream, NA, Nmu, Amut);
  hipLaunchKernelGGL(main_k, dim3(N_ / 128, K_ / 32), dim3(512), 0, stream, Ab, Xbt, Amut, sqws);
  hipLaunchKernelGGL(softmax_k, dim3(N_ / 32), dim3(256), 0, stream, sqws, g, out);
}

// Round 3
// 163.077 us; speedup vs baseline: 1.4885x; 1.4885x over previous
//
#include <hip/hip_runtime.h>
#include <hip/hip_bf16.h>

#define D_ 128
#define N_ 8192
#define K_ 256

typedef __attribute__((ext_vector_type(8))) short sh8;   // 8 bf16 = 4 VGPRs
typedef __attribute__((ext_vector_type(4))) float f4;    // 4 fp32

__device__ __forceinline__ unsigned short f2bf(float f) {
  union { float f; unsigned u; } x; x.f = f;
  unsigned r = x.u + 0x7fffu + ((x.u >> 16) & 1u);       // RNE
  return (unsigned short)(r >> 16);
}

// ---------------------------------------------------------------------------
// prep_x: X (fp32 [D][N]) -> Xbt (bf16 [N][D]) transpose, copy X -> out rows 0..D-1,
// and zero Amut (for amu_k's atomics). grid (N/64, D/64), block 256
__global__ void prep_x_k(const float* __restrict__ X, float* __restrict__ out,
                         unsigned short* __restrict__ Xbt, float* __restrict__ Amut) {
  __shared__ float tile[64][65];
  const int n0 = blockIdx.x * 64;
  const int e0 = blockIdx.y * 64;
  const int t = threadIdx.x;
  // zero 128 floats of Amut per block (256 blocks x 128 = 32768 = K_*D_)
  {
    int id = blockIdx.y * (N_ / 64) + blockIdx.x;
    if (t < 128) Amut[(size_t)id * 128 + t] = 0.f;
  }
  const int col = t & 63;
  const int r4 = t >> 6;
  for (int rr = 0; rr < 64; rr += 4) {
    int e = rr + r4;
    float v = X[(size_t)(e0 + e) * N_ + n0 + col];
    tile[e][col] = v;
    out[(size_t)(e0 + e) * N_ + n0 + col] = v;   // exact fp32 copy of X
  }
  __syncthreads();
  const int chunk = t & 15;
  for (int iter = 0; iter < 4; ++iter) {
    int nl = iter * 16 + (t >> 4);
    ushort4 w;
    w.x = f2bf(tile[chunk * 4 + 0][nl]);
    w.y = f2bf(tile[chunk * 4 + 1][nl]);
    w.z = f2bf(tile[chunk * 4 + 2][nl]);
    w.w = f2bf(tile[chunk * 4 + 3][nl]);
    *(ushort4*)&Xbt[(size_t)(n0 + nl) * D_ + e0 + chunk * 4] = w;
  }
}

// ---------------------------------------------------------------------------
// prep_a: N_A (fp32 [D][D][K], layout d,e,c) -> Ab (bf16 [K][D][D], layout c,d,e)
// grid (K/64, D/64, D), block 256
__global__ void prep_a_k(const float* __restrict__ NA, unsigned short* __restrict__ Ab) {
  __shared__ float tile[64][65];   // [e][c]
  const int c0 = blockIdx.x * 64;
  const int e0 = blockIdx.y * 64;
  const int d  = blockIdx.z;
  const int t = threadIdx.x;
  const int cc = t & 63;
  const int r4 = t >> 6;
  const size_t dbase = (size_t)d * D_ * K_;
  for (int rr = 0; rr < 64; rr += 4) {
    int e = rr + r4;
    tile[e][cc] = NA[dbase + (size_t)(e0 + e) * K_ + c0 + cc];
  }
  __syncthreads();
  const int chunk = t & 15;
  for (int iter = 0; iter < 4; ++iter) {
    int cl = iter * 16 + (t >> 4);
    ushort4 w;
    w.x = f2bf(tile[chunk * 4 + 0][cl]);
    w.y = f2bf(tile[chunk * 4 + 1][cl]);
    w.z = f2bf(tile[chunk * 4 + 2][cl]);
    w.w = f2bf(tile[chunk * 4 + 3][cl]);
    *(ushort4*)&Ab[(size_t)(c0 + cl) * D_ * D_ + (size_t)d * D_ + e0 + chunk * 4] = w;
  }
}

// ---------------------------------------------------------------------------
// amu: Amut[c][d] += sum_e NA[d][e][c]*Nmu[e][c] over this block's 32 e.
// grid (D, 4), block K. Amut pre-zeroed by prep_x_k.
__global__ void amu_k(const float* __restrict__ NA, const float* __restrict__ Nmu,
                      float* __restrict__ Amut) {
  const int d = blockIdx.x;
  const int e0 = blockIdx.y * 32;
  const int c = threadIdx.x;
  const size_t dbase = (size_t)d * D_ * K_;
  float s0 = 0.f, s1 = 0.f;
#pragma unroll 8
  for (int e = 0; e < 16; ++e) {
    s0 += NA[dbase + (size_t)(e0 + e) * K_ + c] * Nmu[(size_t)(e0 + e) * K_ + c];
    s1 += NA[dbase + (size_t)(e0 + 16 + e) * K_ + c] * Nmu[(size_t)(e0 + 16 + e) * K_ + c];
  }
  atomicAdd(&Amut[(size_t)c * D_ + d], s0 + s1);
}

// ---------------------------------------------------------------------------
// main: for each (n-tile of 128, c-chunk of 32):
//   sq[c][n] = sum_d (sum_e A[d,e,c] X[e,n] - Amu[d,c])^2
// grid (N/128, K/32), block 256 (4 waves). Wave w: d in [w*32, w*32+32), j in [0,128).
// NO per-c barrier: wave-private partials -> LDS, one barrier + reduce at the end.
// A-loads for c+1 issued right after c's MFMAs (regs dead), hidden by epilogue.
__global__ __launch_bounds__(256, 2) void main_k(
    const unsigned short* __restrict__ Ab, const unsigned short* __restrict__ Xbt,
    const float* __restrict__ Amut, float* __restrict__ sqws) {
  __shared__ float part[4][32][128];   // 64 KB: [wave(d-slice)][ci][j]
  const int t = threadIdx.x;
  const int w = t >> 6;
  const int L = t & 63;
  const int m = L & 15;        // MFMA row/col lane index
  const int q = L >> 4;        // quad
  const int n0 = blockIdx.x * 128;
  const int c0 = blockIdx.y * 32;

  // X B-fragments in registers for entire c-loop (128 VGPRs):
  // lane holds n = jt*16+m, k = ks*32 + q*8 + i -> contiguous 16B of Xbt[n][e]
  sh8 xf[8][4];
  {
    const unsigned short* xb = Xbt + (size_t)(n0 + m) * D_ + q * 8;
#pragma unroll
    for (int jt = 0; jt < 8; ++jt)
#pragma unroll
      for (int ks = 0; ks < 4; ++ks)
        xf[jt][ks] = *(const sh8*)&xb[(size_t)jt * 16 * D_ + ks * 32];
  }

  const unsigned short* Ap = Ab + (size_t)c0 * D_ * D_ + (size_t)(w * 32 + m) * D_ + q * 8;
  const float* amup = Amut + (size_t)c0 * D_ + w * 32 + q * 4;

  // preload A fragments for ci=0
  sh8 a0[4], a1[4];
#pragma unroll
  for (int ks = 0; ks < 4; ++ks) {
    a0[ks] = *(const sh8*)&Ap[ks * 32];
    a1[ks] = *(const sh8*)&Ap[(size_t)16 * D_ + ks * 32];
  }

  const f4 zero = {0.f, 0.f, 0.f, 0.f};

  for (int ci = 0; ci < 32; ++ci) {
    // amu for current c: loaded at loop top, used ~1100 cyc later (after MFMAs)
    f4 amu0 = *(const f4*)amup;
    f4 amu1 = *(const f4*)(amup + 16);
    amup += D_;

    f4 acc[2][8];
#pragma unroll
    for (int jt = 0; jt < 8; ++jt) { acc[0][jt] = zero; acc[1][jt] = zero; }

#pragma unroll
    for (int ks = 0; ks < 4; ++ks) {
#pragma unroll
      for (int jt = 0; jt < 8; ++jt) {
        acc[0][jt] = __builtin_amdgcn_mfma_f32_16x16x32_bf16(a0[ks], xf[jt][ks], acc[0][jt], 0, 0, 0);
        acc[1][jt] = __builtin_amdgcn_mfma_f32_16x16x32_bf16(a1[ks], xf[jt][ks], acc[1][jt], 0, 0, 0);
      }
    }

    // prefetch A for ci+1 into the (now dead) a regs; epilogue hides the latency
    if (ci < 31) {
      Ap += D_ * D_;
#pragma unroll
      for (int ks = 0; ks < 4; ++ks) {
        a0[ks] = *(const sh8*)&Ap[ks * 32];
        a1[ks] = *(const sh8*)&Ap[(size_t)16 * D_ + ks * 32];
      }
    }

    // epilogue: subtract Amu, square, reduce over this wave's 32 d rows.
    // C/D layout: col j = jt*16 + m, row d = w*32 + tile*16 + q*4 + r
    float ps[8];
#pragma unroll
    for (int jt = 0; jt < 8; ++jt) {
      float s = 0.f;
#pragma unroll
      for (int r = 0; r < 4; ++r) {
        float v0 = acc[0][jt][r] - amu0[r];
        float v1 = acc[1][jt][r] - amu1[r];
        s += v0 * v0 + v1 * v1;
      }
      s += __shfl_xor(s, 16, 64);   // sum quads: full 32-d partial, replicated over q
      s += __shfl_xor(s, 32, 64);
      ps[jt] = s;
    }
    // lane (q,m) stores cols j = q*32+m (ps[2q]) and q*32+16+m (ps[2q+1])
    float sel0 = (q == 0) ? ps[0] : (q == 1) ? ps[2] : (q == 2) ? ps[4] : ps[6];
    float sel1 = (q == 0) ? ps[1] : (q == 1) ? ps[3] : (q == 2) ? ps[5] : ps[7];
    part[w][ci][q * 32 + m] = sel0;
    part[w][ci][q * 32 + 16 + m] = sel1;
  }

  __syncthreads();   // the ONLY barrier
  // cross-wave reduce: 32 c x 128 j, 256 threads -> 16 rows each
  const int j = t & 127;
  const int cg = t >> 7;
#pragma unroll
  for (int k = 0; k < 16; ++k) {
    int ci = cg * 16 + k;
    float s = part[0][ci][j] + part[1][ci][j] + part[2][ci][j] + part[3][ci][j];
    sqws[(size_t)(c0 + ci) * N_ + n0 + j] = s;
  }
}

// ---------------------------------------------------------------------------
// softmax over c per n; writes Pi to out rows D_..D_+K_-1
// grid (N/32), block 256. thread t: n_loc = t&31, c-group = t>>5 (32 c each)
__global__ __launch_bounds__(256) void softmax_k(const float* __restrict__ sqws,
                                                 const float* __restrict__ gptr,
                                                 float* __restrict__ out) {
  __shared__ float s_ld[K_][32];   // 32 KB
  __shared__ float red[8][32];
  __shared__ float red2[8][32];
  const int t = threadIdx.x;
  const int n0 = blockIdx.x * 32;
  const float gamma = *gptr;
  const int nl = t & 31;
  const int cg = t >> 5;           // 8 groups of 32 c
  for (int it = 0; it < 32; ++it) {
    int c = it * 8 + cg;
    s_ld[c][nl] = sqws[(size_t)c * N_ + n0 + nl];
  }
  __syncthreads();
  float mxp = -1e30f;
  for (int cc = 0; cc < 32; ++cc)
    mxp = fmaxf(mxp, gamma * s_ld[cg * 32 + cc][nl]);
  red[cg][nl] = mxp;
  __syncthreads();
  float mx = red[0][nl];
#pragma unroll
  for (int g2 = 1; g2 < 8; ++g2) mx = fmaxf(mx, red[g2][nl]);
  float z = 0.f;
  for (int cc = 0; cc < 32; ++cc) {
    int c = cg * 32 + cc;
    float e = __expf(gamma * s_ld[c][nl] - mx);
    s_ld[c][nl] = e;
    z += e;
  }
  red2[cg][nl] = z;
  __syncthreads();
  float zz = red2[0][nl];
#pragma unroll
  for (int g2 = 1; g2 < 8; ++g2) zz += red2[g2][nl];
  float rz = 1.f / zz;
  for (int cc = 0; cc < 32; ++cc) {
    int c = cg * 32 + cc;
    out[(size_t)(D_ + c) * N_ + n0 + nl] = s_ld[c][nl] * rz;
  }
}

// ---------------------------------------------------------------------------
extern "C" void kernel_launch(void* const* d_in, const int* in_sizes, int n_in,
                              void* d_out, int out_size, void* d_ws, size_t ws_size,
                              hipStream_t stream) {
  const float* X   = (const float*)d_in[0];
  const float* NA  = (const float*)d_in[1];
  const float* Nmu = (const float*)d_in[2];
  const float* g   = (const float*)d_in[3];
  float* out = (float*)d_out;
  char* ws = (char*)d_ws;

  unsigned short* Xbt = (unsigned short*)(ws);                 // 2 MB
  unsigned short* Ab  = (unsigned short*)(ws + 2097152);       // 8.39 MB
  float* Amut         = (float*)(ws + 10485760);               // 128 KB
  float* sqws         = (float*)(ws + 10616832);               // 8.39 MB

  hipLaunchKernelGGL(prep_x_k, dim3(N_ / 64, D_ / 64), dim3(256), 0, stream, X, out, Xbt, Amut);
  hipLaunchKernelGGL(prep_a_k, dim3(K_ / 64, D_ / 64, D_), dim3(256), 0, stream, NA, Ab);
  hipLaunchKernelGGL(amu_k, dim3(D_, 4), dim3(K_), 0, stream, NA, Nmu, Amut);
  hipLaunchKernelGGL(main_k, dim3(N_ / 128, K_ / 32), dim3(256), 0, stream, Ab, Xbt, Amut, sqws);
  hipLaunchKernelGGL(softmax_k, dim3(N_ / 32), dim3(256), 0, stream, sqws, g, out);
}

// Round 4
// 147.988 us; speedup vs baseline: 1.6403x; 1.1020x over previous
//
#include <hip/hip_runtime.h>
#include <hip/hip_bf16.h>

#define D_ 128
#define N_ 8192
#define K_ 256

typedef __attribute__((ext_vector_type(8))) short sh8;   // 8 bf16 = 4 VGPRs
typedef __attribute__((ext_vector_type(4))) float f4;    // 4 fp32

__device__ __forceinline__ unsigned short f2bf(float f) {
  union { float f; unsigned u; } x; x.f = f;
  unsigned r = x.u + 0x7fffu + ((x.u >> 16) & 1u);       // RNE
  return (unsigned short)(r >> 16);
}

__device__ __forceinline__ float bf2f(unsigned short h) {
  union { unsigned u; float f; } x; x.u = ((unsigned)h) << 16;
  return x.f;
}

// ---------------------------------------------------------------------------
// prep_x: X (fp32 [D][N]) -> Xbt (bf16 [N][D]) transpose, copy X -> out rows 0..D-1
// grid (N/64, D/64), block 256
__global__ void prep_x_k(const float* __restrict__ X, float* __restrict__ out,
                         unsigned short* __restrict__ Xbt) {
  __shared__ float tile[64][65];
  const int n0 = blockIdx.x * 64;
  const int e0 = blockIdx.y * 64;
  const int t = threadIdx.x;
  const int col = t & 63;
  const int r4 = t >> 6;
  for (int rr = 0; rr < 64; rr += 4) {
    int e = rr + r4;
    float v = X[(size_t)(e0 + e) * N_ + n0 + col];
    tile[e][col] = v;
    out[(size_t)(e0 + e) * N_ + n0 + col] = v;   // exact fp32 copy of X
  }
  __syncthreads();
  const int chunk = t & 15;
  for (int iter = 0; iter < 4; ++iter) {
    int nl = iter * 16 + (t >> 4);
    ushort4 w;
    w.x = f2bf(tile[chunk * 4 + 0][nl]);
    w.y = f2bf(tile[chunk * 4 + 1][nl]);
    w.z = f2bf(tile[chunk * 4 + 2][nl]);
    w.w = f2bf(tile[chunk * 4 + 3][nl]);
    *(ushort4*)&Xbt[(size_t)(n0 + nl) * D_ + e0 + chunk * 4] = w;
  }
}

// ---------------------------------------------------------------------------
// prep_a: N_A (fp32 [D][D][K], layout d,e,c) -> Ab (bf16 [K][D][D], layout c,d,e)
// grid (K/64, D/64, D), block 256
__global__ void prep_a_k(const float* __restrict__ NA, unsigned short* __restrict__ Ab) {
  __shared__ float tile[64][65];   // [e][c]
  const int c0 = blockIdx.x * 64;
  const int e0 = blockIdx.y * 64;
  const int d  = blockIdx.z;
  const int t = threadIdx.x;
  const int cc = t & 63;
  const int r4 = t >> 6;
  const size_t dbase = (size_t)d * D_ * K_;
  for (int rr = 0; rr < 64; rr += 4) {
    int e = rr + r4;
    tile[e][cc] = NA[dbase + (size_t)(e0 + e) * K_ + c0 + cc];
  }
  __syncthreads();
  const int chunk = t & 15;
  for (int iter = 0; iter < 4; ++iter) {
    int cl = iter * 16 + (t >> 4);
    ushort4 w;
    w.x = f2bf(tile[chunk * 4 + 0][cl]);
    w.y = f2bf(tile[chunk * 4 + 1][cl]);
    w.z = f2bf(tile[chunk * 4 + 2][cl]);
    w.w = f2bf(tile[chunk * 4 + 3][cl]);
    *(ushort4*)&Ab[(size_t)(c0 + cl) * D_ * D_ + (size_t)d * D_ + e0 + chunk * 4] = w;
  }
}

// ---------------------------------------------------------------------------
// amu v2: Amut[c][d] = sum_e Ab[c][d][e] * N_mu[e][c]  (bf16 A — consistent with
// the A used in the MFMA, so N_eval error is a single rounding of A).
// grid (K), block (D). No atomics.
__global__ void amu_k(const unsigned short* __restrict__ Ab,
                      const float* __restrict__ Nmu, float* __restrict__ Amut) {
  __shared__ float mu[D_];
  const int c = blockIdx.x;
  const int t = threadIdx.x;     // = d
  mu[t] = Nmu[(size_t)t * K_ + c];
  __syncthreads();
  const unsigned short* row = Ab + (size_t)c * D_ * D_ + (size_t)t * D_;
  float s0 = 0.f, s1 = 0.f;
  for (int e0 = 0; e0 < D_; e0 += 16) {
    sh8 v0 = *(const sh8*)&row[e0];
    sh8 v1 = *(const sh8*)&row[e0 + 8];
#pragma unroll
    for (int i = 0; i < 8; ++i) {
      s0 += bf2f((unsigned short)v0[i]) * mu[e0 + i];
      s1 += bf2f((unsigned short)v1[i]) * mu[e0 + 8 + i];
    }
  }
  Amut[(size_t)c * D_ + t] = s0 + s1;
}

// ---------------------------------------------------------------------------
// main: sq[c][n] = sum_d (sum_e A[d,e,c] X[e,n] - Amu[d,c])^2
// grid (N/256, K/8), block 256 (4 waves). Wave w: j in [w*64, w*64+64), ALL 128 d.
// Per c: stage A[c] plane (32KB) into LDS in FRAGMENT ORDER via global_load_lds
// (we pick per-lane source addresses, so ds_read_b128 is lane-contiguous: zero
// bank conflicts, one base register + immediate offsets). No cross-wave reduce.
__global__ __launch_bounds__(256, 4) void main_k(
    const unsigned short* __restrict__ Ab, const unsigned short* __restrict__ Xbt,
    const float* __restrict__ Amut, float* __restrict__ sqws) {
  __shared__ unsigned short Asw[16384];   // 32 KB, frag-ordered: slot (dt*4+ks)*1024 + L*16
  __shared__ float amus[D_];              // 512 B, plain row
  const int t = threadIdx.x;
  const int w = t >> 6;
  const int L = t & 63;
  const int m = L & 15;
  const int q = L >> 4;
  const int n0 = blockIdx.x * 256;
  const int c0 = blockIdx.y * 8;

  // persistent X B-fragments: wave w covers j = n0 + w*64 + jt*16 + m, k = ks*32+q*8
  sh8 xf[4][4];
  {
    const unsigned short* xb = Xbt + (size_t)(n0 + w * 64 + m) * D_ + q * 8;
#pragma unroll
    for (int jt = 0; jt < 4; ++jt)
#pragma unroll
      for (int ks = 0; ks < 4; ++ks)
        xf[jt][ks] = *(const sh8*)&xb[(size_t)jt * 16 * D_ + ks * 32];
  }

  // staging source byte-offsets: thread t stages slots s = t + 256*it (16B each).
  // slot s: lane L = s&63 (== this thread's L), dtks = s>>6 = (t>>6) + 4*it,
  // content = plane bytes at d*256 + ks*64 + q*16, d = dt*16 + m.
  int soff[8];
#pragma unroll
  for (int it = 0; it < 8; ++it) {
    int dtks = (t >> 6) + it * 4;
    int dt = dtks >> 2, ks = dtks & 3;
    soff[it] = (dt * 16 + m) * 256 + ks * 64 + q * 16;
  }
  const char* aplane = (const char*)(Ab + (size_t)c0 * D_ * D_);

  // stage c0
#pragma unroll
  for (int it = 0; it < 8; ++it)
    __builtin_amdgcn_global_load_lds((const unsigned int*)(aplane + soff[it]),
                                     (unsigned int*)((char*)Asw + it * 4096 + w * 1024),
                                     16, 0, 0);
  if (t < 32)
    __builtin_amdgcn_global_load_lds((const unsigned int*)(Amut + (size_t)c0 * D_ + t * 4),
                                     (unsigned int*)amus, 16, 0, 0);

  const f4 zero = {0.f, 0.f, 0.f, 0.f};
  const char* abase = (const char*)Asw + L * 16;

  for (int ci = 0; ci < 8; ++ci) {
    __syncthreads();   // staging(ci) complete (compiler drains vmcnt before barrier)

    float ss0 = 0.f, ss1 = 0.f, ss2 = 0.f, ss3 = 0.f;
#pragma unroll
    for (int dt = 0; dt < 8; ++dt) {
      sh8 afr[4];
#pragma unroll
      for (int ks = 0; ks < 4; ++ks)
        afr[ks] = *(const sh8*)(abase + (dt * 4 + ks) * 1024);
      f4 amu = *(const f4*)&amus[dt * 16 + q * 4];
#pragma unroll
      for (int jt = 0; jt < 4; ++jt) {
        f4 acc = __builtin_amdgcn_mfma_f32_16x16x32_bf16(afr[0], xf[jt][0], zero, 0, 0, 0);
        acc = __builtin_amdgcn_mfma_f32_16x16x32_bf16(afr[1], xf[jt][1], acc, 0, 0, 0);
        acc = __builtin_amdgcn_mfma_f32_16x16x32_bf16(afr[2], xf[jt][2], acc, 0, 0, 0);
        acc = __builtin_amdgcn_mfma_f32_16x16x32_bf16(afr[3], xf[jt][3], acc, 0, 0, 0);
        float v0 = acc[0] - amu[0];
        float v1 = acc[1] - amu[1];
        float v2 = acc[2] - amu[2];
        float v3 = acc[3] - amu[3];
        float sj = v0 * v0 + v1 * v1 + v2 * v2 + v3 * v3;
        if (jt == 0) ss0 += sj; else if (jt == 1) ss1 += sj;
        else if (jt == 2) ss2 += sj; else ss3 += sj;
      }
    }
    // cross-quad reduce: each lane currently has sum over 32 d-rows (its q's rows
    // across 8 dt); xor-16 and xor-32 complete the 128-d sum (replicated over q).
    ss0 += __shfl_xor(ss0, 16, 64);  ss0 += __shfl_xor(ss0, 32, 64);
    ss1 += __shfl_xor(ss1, 16, 64);  ss1 += __shfl_xor(ss1, 32, 64);
    ss2 += __shfl_xor(ss2, 16, 64);  ss2 += __shfl_xor(ss2, 32, 64);
    ss3 += __shfl_xor(ss3, 16, 64);  ss3 += __shfl_xor(ss3, 32, 64);
    // quad q stores col-tile jt=q: j = w*64 + q*16 + m = w*64 + L  (coalesced 256B/wave)
    float sel = (q == 0) ? ss0 : (q == 1) ? ss1 : (q == 2) ? ss2 : ss3;
    sqws[(size_t)(c0 + ci) * N_ + n0 + w * 64 + L] = sel;

    __syncthreads();   // all waves done reading Asw/amus for ci
    if (ci < 7) {
      aplane += D_ * D_ * 2;   // next c plane (32 KB)
#pragma unroll
      for (int it = 0; it < 8; ++it)
        __builtin_amdgcn_global_load_lds((const unsigned int*)(aplane + soff[it]),
                                         (unsigned int*)((char*)Asw + it * 4096 + w * 1024),
                                         16, 0, 0);
      if (t < 32)
        __builtin_amdgcn_global_load_lds(
            (const unsigned int*)(Amut + (size_t)(c0 + ci + 1) * D_ + t * 4),
            (unsigned int*)amus, 16, 0, 0);
    }
  }
}

// ---------------------------------------------------------------------------
// softmax over c per n; writes Pi to out rows D_..D_+K_-1
// grid (N/32), block 256. thread t: n_loc = t&31, c-group = t>>5 (32 c each)
__global__ __launch_bounds__(256) void softmax_k(const float* __restrict__ sqws,
                                                 const float* __restrict__ gptr,
                                                 float* __restrict__ out) {
  __shared__ float s_ld[K_][32];   // 32 KB
  __shared__ float red[8][32];
  __shared__ float red2[8][32];
  const int t = threadIdx.x;
  const int n0 = blockIdx.x * 32;
  const float gamma = *gptr;
  const int nl = t & 31;
  const int cg = t >> 5;           // 8 groups of 32 c
  for (int it = 0; it < 32; ++it) {
    int c = it * 8 + cg;
    s_ld[c][nl] = sqws[(size_t)c * N_ + n0 + nl];
  }
  __syncthreads();
  float mxp = -1e30f;
  for (int cc = 0; cc < 32; ++cc)
    mxp = fmaxf(mxp, gamma * s_ld[cg * 32 + cc][nl]);
  red[cg][nl] = mxp;
  __syncthreads();
  float mx = red[0][nl];
#pragma unroll
  for (int g2 = 1; g2 < 8; ++g2) mx = fmaxf(mx, red[g2][nl]);
  float z = 0.f;
  for (int cc = 0; cc < 32; ++cc) {
    int c = cg * 32 + cc;
    float e = __expf(gamma * s_ld[c][nl] - mx);
    s_ld[c][nl] = e;
    z += e;
  }
  red2[cg][nl] = z;
  __syncthreads();
  float zz = red2[0][nl];
#pragma unroll
  for (int g2 = 1; g2 < 8; ++g2) zz += red2[g2][nl];
  float rz = 1.f / zz;
  for (int cc = 0; cc < 32; ++cc) {
    int c = cg * 32 + cc;
    out[(size_t)(D_ + c) * N_ + n0 + nl] = s_ld[c][nl] * rz;
  }
}

// ---------------------------------------------------------------------------
extern "C" void kernel_launch(void* const* d_in, const int* in_sizes, int n_in,
                              void* d_out, int out_size, void* d_ws, size_t ws_size,
                              hipStream_t stream) {
  const float* X   = (const float*)d_in[0];
  const float* NA  = (const float*)d_in[1];
  const float* Nmu = (const float*)d_in[2];
  const float* g   = (const float*)d_in[3];
  float* out = (float*)d_out;
  char* ws = (char*)d_ws;

  unsigned short* Xbt = (unsigned short*)(ws);                 // 2 MB
  unsigned short* Ab  = (unsigned short*)(ws + 2097152);       // 8.39 MB
  float* Amut         = (float*)(ws + 10485760);               // 128 KB
  float* sqws         = (float*)(ws + 10616832);               // 8.39 MB

  hipLaunchKernelGGL(prep_x_k, dim3(N_ / 64, D_ / 64), dim3(256), 0, stream, X, out, Xbt);
  hipLaunchKernelGGL(prep_a_k, dim3(K_ / 64, D_ / 64, D_), dim3(256), 0, stream, NA, Ab);
  hipLaunchKernelGGL(amu_k, dim3(K_), dim3(D_), 0, stream, Ab, Nmu, Amut);
  hipLaunchKernelGGL(main_k, dim3(N_ / 256, K_ / 8), dim3(256), 0, stream, Ab, Xbt, Amut, sqws);
  hipLaunchKernelGGL(softmax_k, dim3(N_ / 32), dim3(256), 0, stream, sqws, g, out);
}